// Round 10
// baseline (277.645 us; speedup 1.0000x reference)
//
#include <hip/hip_runtime.h>
#include <hip/hip_bf16.h>
#include <math.h>

#define L_SEQ  2048
#define DMODEL 1024
#define NHEAD  16
#define HEADD  64

typedef __attribute__((ext_vector_type(8))) short short8;
typedef __attribute__((ext_vector_type(4))) short short4v;
typedef __attribute__((ext_vector_type(4))) float f32x4;

// RNE float -> bf16 bits
static __device__ __forceinline__ unsigned short f2bf(float f) {
    unsigned int u = __float_as_uint(f);
    unsigned int r = (u + 0x7fffu + ((u >> 16) & 1u)) >> 16;
    return (unsigned short)r;
}

static __device__ __forceinline__ void dma16(const unsigned short* g, unsigned short* l) {
    __builtin_amdgcn_global_load_lds((const __attribute__((address_space(1))) void*)g,
                                     (__attribute__((address_space(3))) void*)l, 16, 0, 0);
}

// ---------------- fused prep: X->bf16, 4 weights->bf16, RoPE table ----------
__global__ __launch_bounds__(256) void prep(
    const float* __restrict__ query,
    const float* __restrict__ Wq, const float* __restrict__ Wk,
    const float* __restrict__ Wv, const float* __restrict__ Wo,
    unsigned short* __restrict__ xb, unsigned short* __restrict__ wdst,
    float* __restrict__ rope)
{
    int gid = blockIdx.x * 256 + threadIdx.x;
    if (gid < 2097152) {
        float4 v = reinterpret_cast<const float4*>(query)[gid];
        ushort4 o;
        o.x = f2bf(v.x); o.y = f2bf(v.y); o.z = f2bf(v.z); o.w = f2bf(v.w);
        reinterpret_cast<ushort4*>(xb)[gid] = o;
    } else if (gid < 2097152 + 1048576) {
        int i = gid - 2097152;
        int which = i >> 18;                  // 262144 groups per weight
        const float* src = which == 0 ? Wq : which == 1 ? Wk : which == 2 ? Wv : Wo;
        float4 v = reinterpret_cast<const float4*>(src)[i & 262143];
        ushort4 o;
        o.x = f2bf(v.x); o.y = f2bf(v.y); o.z = f2bf(v.z); o.w = f2bf(v.w);
        reinterpret_cast<ushort4*>(wdst)[i] = o;
    } else if (gid < 2097152 + 1048576 + 65536) {
        int i = gid - (2097152 + 1048576);
        int lpos = i >> 5, i2 = i & 31;
        float inv_f = expf(-0.28782313662425574f * (float)i2);  // 10000^(-i2/32)
        float ang = (float)lpos * inv_f;
        rope[2 * i]     = cosf(ang);
        rope[2 * i + 1] = sinf(ang);
    }
}

// ---------------- fused QKV projection -------------------------------------
// Round 10: 128x256 tile, 8 waves (2Mx4N), BK=32, ring-3 LDS (72KB -> 2
// blocks/CU = 16 waves/CU), counted vmcnt(3), 2 barriers/iter. Each wave owns
// a 64x64 strip (acc[4][4], same proven register shape); barriers amortized
// over 2x output vs round 9. L2-topology swizzle + LDS-staged coalesced
// epilogue (two 128-col passes) retained.
#define BKP 32

__global__ __launch_bounds__(512, 4) void proj_qkv(
    const unsigned short* __restrict__ X,
    const unsigned short* __restrict__ Wqkv,
    const float* __restrict__ bq_,
    const float* __restrict__ bk_,
    const float* __restrict__ bv_,
    const float* __restrict__ rope,
    unsigned short* __restrict__ Qb,
    unsigned short* __restrict__ Kb,
    unsigned short* __restrict__ Vr)
{
    // 72 KB pool: A ring 3x4096 shorts | B ring 3x8192; epilogue tile 128x136
    __shared__ unsigned short pool[36864];
    unsigned short* a_ring = pool;            // slot s: + s*4096
    unsigned short* b_ring = pool + 12288;    // slot s: + s*8192

    const int tid  = threadIdx.x;
    const int lane = tid & 63;
    const int w    = tid >> 6;          // 0..7
    const int wm   = w & 1, wn = w >> 1;     // 2M x 4N
    const int quad = lane >> 4, l16 = lane & 15;

    // L2-topology swizzle: xcd = orig&7 owns by in [xcd*8, xcd*8+8).
    // nwg = 768, 768 % 8 == 0 -> bijective.
    const int orig = blockIdx.y * 12 + blockIdx.x;
    const int xcd  = orig & 7;
    const int k    = orig >> 3;         // 0..95
    const int by   = xcd * 8 + (k & 7); // 0..63
    const int bxp  = k >> 3;            // 0..11 (n-pair index)
    const int m0   = by * 128;
    const int n0   = bxp * 256;

    const int sel = bxp >> 2;           // wave-uniform: 0=Q 1=K 2=V
    const float* bias   = sel == 0 ? bq_ : (sel == 1 ? bk_ : bv_);
    unsigned short* out = sel == 0 ? Qb  : (sel == 1 ? Kb  : Vr);

    const int st_row = lane >> 2;                                   // 0..15
    const int st_col = (((lane & 3) ^ ((lane >> 3) & 3)) << 3);     // shorts
    const int rd = ((quad ^ ((l16 >> 1) & 3)) << 3);

    f32x4 acc[4][4];
#pragma unroll
    for (int i = 0; i < 4; ++i)
#pragma unroll
        for (int j = 0; j < 4; ++j) acc[i][j] = (f32x4){0.f, 0.f, 0.f, 0.f};

    // staging: A 128 rows/8 waves = 16 rows = 1 dma; B 256/8 = 32 rows = 2 dma
    const unsigned short* Xs = X    + (size_t)(m0 + w * 16 + st_row) * DMODEL + st_col;
    const unsigned short* Ws = Wqkv + (size_t)(n0 + w * 32 + st_row) * DMODEL + st_col;
    const int ldsA  = (w * 16) * BKP;
    const int ldsB0 = (w * 32) * BKP, ldsB1 = (w * 32 + 16) * BKP;

    // ---- prologue: stage tiles 0,1 into slots 0,1 (3 dma/wave each)
#pragma unroll
    for (int p = 0; p < 2; ++p) {
        const int kk = p * BKP;
        dma16(Xs + kk,               a_ring + p * 4096 + ldsA);
        dma16(Ws + kk,               b_ring + p * 8192 + ldsB0);
        dma16(Ws + 16 * DMODEL + kk, b_ring + p * 8192 + ldsB1);
    }
    asm volatile("s_waitcnt vmcnt(3)" ::: "memory");   // tile 0 fully landed
    __builtin_amdgcn_s_barrier();

    for (int kt = 0; kt < 32; ++kt) {
        const int sA = (kt % 3) * 4096;
        const int sB = (kt % 3) * 8192;
        const int pA = ((kt + 2) % 3) * 4096;    // freed at end of iter kt-1
        const int pB = ((kt + 2) % 3) * 8192;
        const int kk = ((kt + 2) & 31) * BKP;    // wrap keeps ledger uniform

        short8 af[4], bf[4];
#pragma unroll
        for (int i = 0; i < 4; ++i)
            af[i] = *reinterpret_cast<const short8*>(
                &a_ring[sA + (wm * 64 + i * 16 + l16) * BKP + rd]);
#pragma unroll
        for (int j = 0; j < 4; ++j)
            bf[j] = *reinterpret_cast<const short8*>(
                &b_ring[sB + (wn * 64 + j * 16 + l16) * BKP + rd]);
        dma16(Xs + kk,               a_ring + pA + ldsA);
        dma16(Ws + kk,               b_ring + pB + ldsB0);
        dma16(Ws + 16 * DMODEL + kk, b_ring + pB + ldsB1);
        __builtin_amdgcn_s_barrier();
        asm volatile("s_waitcnt lgkmcnt(0)" ::: "memory");
        __builtin_amdgcn_sched_barrier(0);
        __builtin_amdgcn_s_setprio(1);
#pragma unroll
        for (int i = 0; i < 4; ++i)
#pragma unroll
            for (int j = 0; j < 4; ++j)
                acc[i][j] = __builtin_amdgcn_mfma_f32_16x16x32_bf16(af[i], bf[j], acc[i][j], 0, 0, 0);
        __builtin_amdgcn_s_setprio(0);
        // boundary: in flight <= 6 (tiles kt+1, kt+2); vmcnt(3) => kt+1 landed
        asm volatile("s_waitcnt vmcnt(3)" ::: "memory");
        __builtin_amdgcn_s_barrier();
    }
    asm volatile("s_waitcnt vmcnt(0)" ::: "memory");   // retire wrapped dummies
    __builtin_amdgcn_s_barrier();   // ALL waves' DMAs landed before pool reuse

    // ---- epilogue: two 128-col passes; LDS tile [128][136], coalesced stores
    const int b     = m0 >> 11;
    const int lpos0 = m0 & (L_SEQ - 1);
#pragma unroll
    for (int t = 0; t < 2; ++t) {
        if ((wn >> 1) == t) {     // waves owning cols t*128..t*128+127
#pragma unroll
            for (int jf = 0; jf < 4; ++jf) {
                int nl = (wn & 1) * 64 + jf * 16 + l16;    // 0..127 in tile
                int nn = (bxp & 3) * 256 + t * 128 + nl;   // 0..1023 in weight
                float bval = bias[nn];
                int d  = nn & (HEADD - 1);
                float sgn = (d & 1) ? 1.0f : -1.0f;
                int i2 = d >> 1;
#pragma unroll
                for (int mf = 0; mf < 4; ++mf) {
#pragma unroll
                    for (int r = 0; r < 4; ++r) {
                        int ml = wm * 64 + mf * 16 + quad * 4 + r;
                        int lpos = (m0 + ml) & (L_SEQ - 1);
                        float v = acc[mf][jf][r] + bval;
                        if (sel < 2) {
                            float p = __shfl_xor(v, 1);   // partner (d^1)
                            float2 cs = *reinterpret_cast<const float2*>(&rope[(size_t)(lpos * 32 + i2) * 2]);
                            v = v * cs.x + sgn * cs.y * p;
                            if (sel == 0) v *= 0.18033688011112042f;  // log2e/8
                        }
                        pool[(sel < 2) ? (ml * 136 + nl) : (nl * 136 + ml)] = f2bf(v);
                    }
                }
            }
        }
        asm volatile("s_waitcnt lgkmcnt(0)" ::: "memory");
        __builtin_amdgcn_s_barrier();
        // store pass: 2048 int4 pieces / 512 threads = 4 each
#pragma unroll
        for (int i = 0; i < 4; ++i) {
            int g   = i * 512 + tid;
            int row = g >> 4;             // 0..127
            int c8  = (g & 15) * 8;       // 0..120
            int4 val = *reinterpret_cast<const int4*>(&pool[row * 136 + c8]);
            size_t addr;
            if (sel < 2) {                // row -> lpos, c8 -> n
                int n_g = (bxp & 3) * 256 + t * 128 + c8;
                int h = n_g >> 6, d = n_g & 63;
                addr = ((size_t)(b * NHEAD + h) * L_SEQ + (lpos0 + row)) * HEADD + d;
            } else {                      // row -> (h,d), c8 -> lpos
                int n_g = (bxp & 3) * 256 + t * 128 + row;
                int h = n_g >> 6, d = n_g & 63;
                addr = ((size_t)(b * NHEAD + h) * HEADD + d) * L_SEQ + lpos0 + c8;
            }
            *reinterpret_cast<int4*>(out + addr) = val;
        }
        asm volatile("s_waitcnt lgkmcnt(0)" ::: "memory");
        __builtin_amdgcn_s_barrier();
    }
}

// ---------------- flash attention (causal), S^T formulation -----------------
// ROUND-8 EXACT: 128 q-rows (two q-blocks) per block per K/V tile; K/V staged
// once for both halves; kf/vf reads shared; branch-free causal masks.
__global__ __launch_bounds__(256) void attn_fwd(
    const unsigned short* __restrict__ Q,
    const unsigned short* __restrict__ K,
    const unsigned short* __restrict__ Vt,
    unsigned short* __restrict__ Oa)
{
    __shared__ unsigned short k_lds[2][64 * 64];   // 2 x 8KB
    __shared__ unsigned short v_lds[2][64 * 64];   // 2 x 8KB
    const int tid  = threadIdx.x;
    const int lane = tid & 63;
    const int w    = tid >> 6;
    const int quad = lane >> 4, l16 = lane & 15;
    const int pair = blockIdx.y;        // 0..7
    const int bh   = blockIdx.x;        // head -> XCD locality (T1)
    const size_t base = (size_t)bh * L_SEQ * HEADD;
    const int b = bh >> 4, h = bh & 15;

    const int srow  = lane >> 3;                 // 0..7
    const int sslot = lane & 7;
    const int ssw   = ((sslot ^ srow) << 3);     // pre-swizzled col offset (shorts)
    const unsigned short* Ksrc = K  + base + (size_t)(w * 8 + srow) * HEADD + ssw;
    const unsigned short* Vsrc = Vt + base + (size_t)(w * 8 + srow) * L_SEQ + ssw;
    const int d0 = (w * 8) * 64;
    const int d1 = (32 + w * 8) * 64;
    const int swr = (l16 & 7);                   // read-side row XOR key

    for (int half = 0; half < 2; ++half) {
        const int s = half ? (15 - pair) : pair;   // q super-block (128 rows)
        const int qrow0 = s * 128 + w * 16 + l16;
        const int qrow1 = qrow0 + 64;
        const int kbmax = 2 * s + 1;

        short8 qf0[2], qf1[2];
#pragma unroll
        for (int ks = 0; ks < 2; ++ks) {
            qf0[ks] = *reinterpret_cast<const short8*>(Q + base + (size_t)qrow0 * HEADD + ks * 32 + quad * 8);
            qf1[ks] = *reinterpret_cast<const short8*>(Q + base + (size_t)qrow1 * HEADD + ks * 32 + quad * 8);
        }

        f32x4 o0[4], o1[4];
#pragma unroll
        for (int nt = 0; nt < 4; ++nt) {
            o0[nt] = (f32x4){0.f, 0.f, 0.f, 0.f};
            o1[nt] = (f32x4){0.f, 0.f, 0.f, 0.f};
        }
        float lsum0 = 0.f, lsum1 = 0.f;

        // prologue: stage tile 0 -> buf 0
        dma16(Ksrc,                 &k_lds[0][d0]);
        dma16(Ksrc + 32 * HEADD,    &k_lds[0][d1]);
        dma16(Vsrc,                 &v_lds[0][d0]);
        dma16(Vsrc + 32 * L_SEQ,    &v_lds[0][d1]);
        asm volatile("s_waitcnt vmcnt(0)" ::: "memory");
        __builtin_amdgcn_s_barrier();

        int cur = 0;
        for (int kb = 0; kb <= kbmax; ++kb) {
            const int kn = (kb + 1) <= kbmax ? (kb + 1) : 0;
            const int nb = cur ^ 1;
            dma16(Ksrc + (size_t)(kn * 64) * HEADD,        &k_lds[nb][d0]);
            dma16(Ksrc + (size_t)(kn * 64 + 32) * HEADD,   &k_lds[nb][d1]);
            dma16(Vsrc + kn * 64,                          &v_lds[nb][d0]);
            dma16(Vsrc + kn * 64 + 32 * L_SEQ,             &v_lds[nb][d1]);

            f32x4 st0[4], st1[4];
#pragma unroll
            for (int nt = 0; nt < 4; ++nt) {
                st0[nt] = (f32x4){0.f, 0.f, 0.f, 0.f};
                st1[nt] = (f32x4){0.f, 0.f, 0.f, 0.f};
            }
            __builtin_amdgcn_s_setprio(1);
#pragma unroll
            for (int ks = 0; ks < 2; ++ks)
#pragma unroll
                for (int nt = 0; nt < 4; ++nt) {
                    short8 kf = *reinterpret_cast<const short8*>(
                        &k_lds[cur][(nt * 16 + l16) * 64 + (((ks * 4 + quad) ^ swr) << 3)]);
                    st0[nt] = __builtin_amdgcn_mfma_f32_16x16x32_bf16(kf, qf0[ks], st0[nt], 0, 0, 0);
                    st1[nt] = __builtin_amdgcn_mfma_f32_16x16x32_bf16(kf, qf1[ks], st1[nt], 0, 0, 0);
                }
            __builtin_amdgcn_s_setprio(0);

            if (kb >= 2 * s) {          // q0 diag (kb==2s) or fully-past (kb==2s+1)
#pragma unroll
                for (int nt = 0; nt < 4; ++nt)
#pragma unroll
                    for (int r = 0; r < 4; ++r) {
                        int seqcol = kb * 64 + nt * 16 + quad * 4 + r;
                        if (seqcol > qrow0) st0[nt][r] = -INFINITY;
                    }
            }
            if (kb == kbmax) {          // q1 diag
#pragma unroll
                for (int nt = 0; nt < 4; ++nt)
#pragma unroll
                    for (int r = 0; r < 4; ++r) {
                        int seqcol = kb * 64 + nt * 16 + quad * 4 + r;
                        if (seqcol > qrow1) st1[nt][r] = -INFINITY;
                    }
            }

            short4v pfrag0[4], pfrag1[4];
#pragma unroll
            for (int nt = 0; nt < 4; ++nt) {
                float p0 = __builtin_amdgcn_exp2f(st0[nt][0]);
                float p1 = __builtin_amdgcn_exp2f(st0[nt][1]);
                float p2 = __builtin_amdgcn_exp2f(st0[nt][2]);
                float p3 = __builtin_amdgcn_exp2f(st0[nt][3]);
                lsum0 += (p0 + p1) + (p2 + p3);
                unsigned u0 = __float_as_uint(p0) + 0x8000u;
                unsigned u1 = __float_as_uint(p1) + 0x8000u;
                unsigned u2 = __float_as_uint(p2) + 0x8000u;
                unsigned u3 = __float_as_uint(p3) + 0x8000u;
                union { unsigned u[2]; short4v v; } pk;
                pk.u[0] = (u0 >> 16) | (u1 & 0xffff0000u);
                pk.u[1] = (u2 >> 16) | (u3 & 0xffff0000u);
                pfrag0[nt] = pk.v;

                float q0e = __builtin_amdgcn_exp2f(st1[nt][0]);
                float q1e = __builtin_amdgcn_exp2f(st1[nt][1]);
                float q2e = __builtin_amdgcn_exp2f(st1[nt][2]);
                float q3e = __builtin_amdgcn_exp2f(st1[nt][3]);
                lsum1 += (q0e + q1e) + (q2e + q3e);
                unsigned v0 = __float_as_uint(q0e) + 0x8000u;
                unsigned v1 = __float_as_uint(q1e) + 0x8000u;
                unsigned v2 = __float_as_uint(q2e) + 0x8000u;
                unsigned v3 = __float_as_uint(q3e) + 0x8000u;
                union { unsigned u[2]; short4v v; } pk1;
                pk1.u[0] = (v0 >> 16) | (v1 & 0xffff0000u);
                pk1.u[1] = (v2 >> 16) | (v3 & 0xffff0000u);
                pfrag1[nt] = pk1.v;
            }

            __builtin_amdgcn_s_setprio(1);
#pragma unroll
            for (int c = 0; c < 4; ++c)
#pragma unroll
                for (int nt2 = 0; nt2 < 4; ++nt2) {
                    short4v vf = *reinterpret_cast<const short4v*>(
                        &v_lds[cur][(nt2 * 16 + l16) * 64 +
                                    (((c * 2 + (quad >> 1)) ^ swr) << 3) + ((quad & 1) << 2)]);
                    o0[nt2] = __builtin_amdgcn_mfma_f32_16x16x16bf16_1k(pfrag0[c], vf, o0[nt2], 0, 0, 0);
                    o1[nt2] = __builtin_amdgcn_mfma_f32_16x16x16bf16_1k(pfrag1[c], vf, o1[nt2], 0, 0, 0);
                }
            __builtin_amdgcn_s_setprio(0);

            asm volatile("s_waitcnt vmcnt(0)" ::: "memory");
            __builtin_amdgcn_s_barrier();
            cur ^= 1;
        }

        // ---- epilogue: row-sum reduce + normalized store, both halves
        lsum0 += __shfl_xor(lsum0, 16);
        lsum0 += __shfl_xor(lsum0, 32);
        lsum1 += __shfl_xor(lsum1, 16);
        lsum1 += __shfl_xor(lsum1, 32);
        float rs0[4], rs1[4];
#pragma unroll
        for (int r = 0; r < 4; ++r) {
            rs0[r] = __shfl(lsum0, quad * 4 + r);
            rs1[r] = __shfl(lsum1, quad * 4 + r);
        }
#pragma unroll
        for (int r = 0; r < 4; ++r) {
            float inv0 = 1.0f / rs0[r];
            float inv1 = 1.0f / rs1[r];
            int lg0 = s * 128 + w * 16 + quad * 4 + r;
            int lg1 = lg0 + 64;
#pragma unroll
            for (int nt = 0; nt < 4; ++nt) {
                int d = nt * 16 + l16;
                Oa[(size_t)(b * L_SEQ + lg0) * DMODEL + h * HEADD + d] = f2bf(o0[nt][r] * inv0);
                Oa[(size_t)(b * L_SEQ + lg1) * DMODEL + h * HEADD + d] = f2bf(o1[nt][r] * inv1);
            }
        }
    }
}

// ---------------- output projection: fp32 out = A @ Wo^T + bo ---------------
// Ring-3 / 1-barrier structure; L2-topology swizzle (by-grouped XCD).
__global__ __launch_bounds__(256) void out_gemm(
    const unsigned short* __restrict__ X,
    const unsigned short* __restrict__ W,
    const float* __restrict__ bias,
    float* __restrict__ out)
{
    __shared__ unsigned short a_lds[3][128 * BKP];
    __shared__ unsigned short b_lds[3][128 * BKP];
    const int tid  = threadIdx.x;
    const int lane = tid & 63;
    const int w    = tid >> 6;
    const int wm   = w & 1, wn = w >> 1;
    const int quad = lane >> 4, l16 = lane & 15;

    // L2-topology swizzle: xcd owns by in [xcd*8, xcd*8+8); bx-major inside
    const int orig = blockIdx.y * 8 + blockIdx.x;
    const int xcd  = orig & 7;
    const int k    = orig >> 3;         // 0..63
    const int m0   = (xcd * 8 + (k & 7)) * 128;
    const int n0   = (k >> 3) * 128;

    const int st_row = lane >> 2;
    const int st_col = (((lane & 3) ^ ((lane >> 3) & 3)) << 3);
    const int rd = ((quad ^ ((l16 >> 1) & 3)) << 3);

    f32x4 acc[4][4];
#pragma unroll
    for (int i = 0; i < 4; ++i)
#pragma unroll
        for (int j = 0; j < 4; ++j) acc[i][j] = (f32x4){0.f, 0.f, 0.f, 0.f};

    const unsigned short* Xs = X + (size_t)(m0 + w * 32 + st_row) * DMODEL + st_col;
    const unsigned short* Ws = W + (size_t)(n0 + w * 32 + st_row) * DMODEL + st_col;
    const int ldsA0 = (w * 32) * BKP, ldsA1 = (w * 32 + 16) * BKP;

#pragma unroll
    for (int p = 0; p < 2; ++p) {
        const int kk = p * BKP;
        dma16(Xs + kk,               &a_lds[p][ldsA0]);
        dma16(Xs + 16 * DMODEL + kk, &a_lds[p][ldsA1]);
        dma16(Ws + kk,               &b_lds[p][ldsA0]);
        dma16(Ws + 16 * DMODEL + kk, &b_lds[p][ldsA1]);
    }
    asm volatile("s_waitcnt vmcnt(4)" ::: "memory");
    __builtin_amdgcn_s_barrier();

    for (int kt = 0; kt < 32; ++kt) {
        const int slot = kt % 3;
        const int ps   = (kt + 2) % 3;
        const int kk   = ((kt + 2) & 31) * BKP;

        dma16(Xs + kk,               &a_lds[ps][ldsA0]);
        dma16(Xs + 16 * DMODEL + kk, &a_lds[ps][ldsA1]);
        dma16(Ws + kk,               &b_lds[ps][ldsA0]);
        dma16(Ws + 16 * DMODEL + kk, &b_lds[ps][ldsA1]);

        short8 af[4], bf[4];
#pragma unroll
        for (int i = 0; i < 4; ++i)
            af[i] = *reinterpret_cast<const short8*>(
                &a_lds[slot][(wm * 64 + i * 16 + l16) * BKP + rd]);
#pragma unroll
        for (int j = 0; j < 4; ++j)
            bf[j] = *reinterpret_cast<const short8*>(
                &b_lds[slot][(wn * 64 + j * 16 + l16) * BKP + rd]);
        asm volatile("s_waitcnt lgkmcnt(0)" ::: "memory");
        __builtin_amdgcn_sched_barrier(0);
        __builtin_amdgcn_s_setprio(1);
#pragma unroll
        for (int i = 0; i < 4; ++i)
#pragma unroll
            for (int j = 0; j < 4; ++j)
                acc[i][j] = __builtin_amdgcn_mfma_f32_16x16x32_bf16(af[i], bf[j], acc[i][j], 0, 0, 0);
        __builtin_amdgcn_s_setprio(0);
        asm volatile("s_waitcnt vmcnt(4)" ::: "memory");
        __builtin_amdgcn_s_barrier();
    }
    asm volatile("s_waitcnt vmcnt(0)" ::: "memory");

#pragma unroll
    for (int nt = 0; nt < 4; ++nt) {
        int n_g = n0 + wn * 64 + nt * 16 + l16;
        float bv = bias[n_g];
#pragma unroll
        for (int mt = 0; mt < 4; ++mt)
#pragma unroll
            for (int r = 0; r < 4; ++r) {
                int m_g = m0 + wm * 64 + mt * 16 + quad * 4 + r;
                out[(size_t)m_g * DMODEL + n_g] = acc[mt][nt][r] + bv;
            }
    }
}

extern "C" void kernel_launch(void* const* d_in, const int* in_sizes, int n_in,
                              void* d_out, int out_size, void* d_ws, size_t ws_size,
                              hipStream_t stream) {
    const float* query = (const float*)d_in[0];
    const float* Wq = (const float*)d_in[1];
    const float* bq = (const float*)d_in[2];
    const float* Wk = (const float*)d_in[3];
    const float* bk = (const float*)d_in[4];
    const float* Wv = (const float*)d_in[5];
    const float* bv = (const float*)d_in[6];
    const float* Wo = (const float*)d_in[7];
    const float* bo = (const float*)d_in[8];
    float* out = (float*)d_out;

    unsigned short* ws  = (unsigned short*)d_ws;
    unsigned short* xb  = ws;                       // 8192*1024
    unsigned short* wqb = xb  + (size_t)8388608;    // 1024*1024 each, CONTIGUOUS wq|wk|wv|wo
    unsigned short* wkb = wqb + 1048576;
    unsigned short* wvb = wkb + 1048576;
    unsigned short* wob = wvb + 1048576;
    unsigned short* Qb  = wob + 1048576;            // [bh][l][d]
    unsigned short* Kb  = Qb  + 8388608;
    unsigned short* Vr  = Kb  + 8388608;            // [bh][d][l] (written directly by proj)
    unsigned short* Ab  = Vr  + 8388608;            // [b][l][h*d]
    float* rope = (float*)(Ab + 8388608);           // 2048*32 float2 = 512 KB

    (void)wkb; (void)wvb;

    // fused prep: X cvt + weight cvt + rope table (one dispatch, 12545 blocks)
    prep<<<12545, 256, 0, stream>>>(query, Wq, Wk, Wv, Wo, xb, wqb, rope);

    // fused QKV GEMM: M=8192 x N=3072, 128x256 tiles -> grid (12, 64) = 768 blocks
    proj_qkv<<<dim3(12, 64), 512, 0, stream>>>(xb, wqb, bq, bk, bv, rope, Qb, Kb, Vr);
    // grid (bh, pair): 128 q-rows/block; s=pair & 15-pair -> 36 tile-units each
    attn_fwd<<<dim3(64, 8), 256, 0, stream>>>(Qb, Kb, Vr, Ab);
    out_gemm<<<dim3(8, 64), 256, 0, stream>>>(Ab, wob, bo, out);
}

// Round 11
// 267.592 us; speedup vs baseline: 1.0376x; 1.0376x over previous
//
#include <hip/hip_runtime.h>
#include <hip/hip_bf16.h>
#include <math.h>

#define L_SEQ  2048
#define DMODEL 1024
#define NHEAD  16
#define HEADD  64

typedef __attribute__((ext_vector_type(8))) short short8;
typedef __attribute__((ext_vector_type(4))) short short4v;
typedef __attribute__((ext_vector_type(4))) float f32x4;

// RNE float -> bf16 bits
static __device__ __forceinline__ unsigned short f2bf(float f) {
    unsigned int u = __float_as_uint(f);
    unsigned int r = (u + 0x7fffu + ((u >> 16) & 1u)) >> 16;
    return (unsigned short)r;
}

static __device__ __forceinline__ void dma16(const unsigned short* g, unsigned short* l) {
    __builtin_amdgcn_global_load_lds((const __attribute__((address_space(1))) void*)g,
                                     (__attribute__((address_space(3))) void*)l, 16, 0, 0);
}

// ---------------- fused prep: X->bf16, 4 weights->bf16, RoPE table ----------
__global__ __launch_bounds__(256) void prep(
    const float* __restrict__ query,
    const float* __restrict__ Wq, const float* __restrict__ Wk,
    const float* __restrict__ Wv, const float* __restrict__ Wo,
    unsigned short* __restrict__ xb, unsigned short* __restrict__ wdst,
    float* __restrict__ rope)
{
    int gid = blockIdx.x * 256 + threadIdx.x;
    if (gid < 2097152) {
        float4 v = reinterpret_cast<const float4*>(query)[gid];
        ushort4 o;
        o.x = f2bf(v.x); o.y = f2bf(v.y); o.z = f2bf(v.z); o.w = f2bf(v.w);
        reinterpret_cast<ushort4*>(xb)[gid] = o;
    } else if (gid < 2097152 + 1048576) {
        int i = gid - 2097152;
        int which = i >> 18;                  // 262144 groups per weight
        const float* src = which == 0 ? Wq : which == 1 ? Wk : which == 2 ? Wv : Wo;
        float4 v = reinterpret_cast<const float4*>(src)[i & 262143];
        ushort4 o;
        o.x = f2bf(v.x); o.y = f2bf(v.y); o.z = f2bf(v.z); o.w = f2bf(v.w);
        reinterpret_cast<ushort4*>(wdst)[i] = o;
    } else if (gid < 2097152 + 1048576 + 65536) {
        int i = gid - (2097152 + 1048576);
        int lpos = i >> 5, i2 = i & 31;
        float inv_f = expf(-0.28782313662425574f * (float)i2);  // 10000^(-i2/32)
        float ang = (float)lpos * inv_f;
        rope[2 * i]     = cosf(ang);
        rope[2 * i + 1] = sinf(ang);
    }
}

// ---------------- fused QKV projection -------------------------------------
// ROUND-10 EXACT (92 us): 128x256 tile, 8 waves (2Mx4N), BK=32, ring-3 LDS
// (72KB -> 2 blocks/CU), counted vmcnt(3), 2 barriers/iter, L2-topology
// swizzle, LDS-staged coalesced epilogue.
#define BKP 32

__global__ __launch_bounds__(512, 4) void proj_qkv(
    const unsigned short* __restrict__ X,
    const unsigned short* __restrict__ Wqkv,
    const float* __restrict__ bq_,
    const float* __restrict__ bk_,
    const float* __restrict__ bv_,
    const float* __restrict__ rope,
    unsigned short* __restrict__ Qb,
    unsigned short* __restrict__ Kb,
    unsigned short* __restrict__ Vr)
{
    // 72 KB pool: A ring 3x4096 shorts | B ring 3x8192; epilogue tile 128x136
    __shared__ unsigned short pool[36864];
    unsigned short* a_ring = pool;            // slot s: + s*4096
    unsigned short* b_ring = pool + 12288;    // slot s: + s*8192

    const int tid  = threadIdx.x;
    const int lane = tid & 63;
    const int w    = tid >> 6;          // 0..7
    const int wm   = w & 1, wn = w >> 1;     // 2M x 4N
    const int quad = lane >> 4, l16 = lane & 15;

    // L2-topology swizzle: xcd = orig&7 owns by in [xcd*8, xcd*8+8).
    const int orig = blockIdx.y * 12 + blockIdx.x;
    const int xcd  = orig & 7;
    const int k    = orig >> 3;         // 0..95
    const int by   = xcd * 8 + (k & 7); // 0..63
    const int bxp  = k >> 3;            // 0..11 (n-pair index)
    const int m0   = by * 128;
    const int n0   = bxp * 256;

    const int sel = bxp >> 2;           // wave-uniform: 0=Q 1=K 2=V
    const float* bias   = sel == 0 ? bq_ : (sel == 1 ? bk_ : bv_);
    unsigned short* out = sel == 0 ? Qb  : (sel == 1 ? Kb  : Vr);

    const int st_row = lane >> 2;                                   // 0..15
    const int st_col = (((lane & 3) ^ ((lane >> 3) & 3)) << 3);     // shorts
    const int rd = ((quad ^ ((l16 >> 1) & 3)) << 3);

    f32x4 acc[4][4];
#pragma unroll
    for (int i = 0; i < 4; ++i)
#pragma unroll
        for (int j = 0; j < 4; ++j) acc[i][j] = (f32x4){0.f, 0.f, 0.f, 0.f};

    // staging: A 128 rows/8 waves = 16 rows = 1 dma; B 256/8 = 32 rows = 2 dma
    const unsigned short* Xs = X    + (size_t)(m0 + w * 16 + st_row) * DMODEL + st_col;
    const unsigned short* Ws = Wqkv + (size_t)(n0 + w * 32 + st_row) * DMODEL + st_col;
    const int ldsA  = (w * 16) * BKP;
    const int ldsB0 = (w * 32) * BKP, ldsB1 = (w * 32 + 16) * BKP;

    // ---- prologue: stage tiles 0,1 into slots 0,1 (3 dma/wave each)
#pragma unroll
    for (int p = 0; p < 2; ++p) {
        const int kk = p * BKP;
        dma16(Xs + kk,               a_ring + p * 4096 + ldsA);
        dma16(Ws + kk,               b_ring + p * 8192 + ldsB0);
        dma16(Ws + 16 * DMODEL + kk, b_ring + p * 8192 + ldsB1);
    }
    asm volatile("s_waitcnt vmcnt(3)" ::: "memory");   // tile 0 fully landed
    __builtin_amdgcn_s_barrier();

    for (int kt = 0; kt < 32; ++kt) {
        const int sA = (kt % 3) * 4096;
        const int sB = (kt % 3) * 8192;
        const int pA = ((kt + 2) % 3) * 4096;    // freed at end of iter kt-1
        const int pB = ((kt + 2) % 3) * 8192;
        const int kk = ((kt + 2) & 31) * BKP;    // wrap keeps ledger uniform

        short8 af[4], bf[4];
#pragma unroll
        for (int i = 0; i < 4; ++i)
            af[i] = *reinterpret_cast<const short8*>(
                &a_ring[sA + (wm * 64 + i * 16 + l16) * BKP + rd]);
#pragma unroll
        for (int j = 0; j < 4; ++j)
            bf[j] = *reinterpret_cast<const short8*>(
                &b_ring[sB + (wn * 64 + j * 16 + l16) * BKP + rd]);
        dma16(Xs + kk,               a_ring + pA + ldsA);
        dma16(Ws + kk,               b_ring + pB + ldsB0);
        dma16(Ws + 16 * DMODEL + kk, b_ring + pB + ldsB1);
        __builtin_amdgcn_s_barrier();
        asm volatile("s_waitcnt lgkmcnt(0)" ::: "memory");
        __builtin_amdgcn_sched_barrier(0);
        __builtin_amdgcn_s_setprio(1);
#pragma unroll
        for (int i = 0; i < 4; ++i)
#pragma unroll
            for (int j = 0; j < 4; ++j)
                acc[i][j] = __builtin_amdgcn_mfma_f32_16x16x32_bf16(af[i], bf[j], acc[i][j], 0, 0, 0);
        __builtin_amdgcn_s_setprio(0);
        // boundary: in flight <= 6 (tiles kt+1, kt+2); vmcnt(3) => kt+1 landed
        asm volatile("s_waitcnt vmcnt(3)" ::: "memory");
        __builtin_amdgcn_s_barrier();
    }
    asm volatile("s_waitcnt vmcnt(0)" ::: "memory");   // retire wrapped dummies
    __builtin_amdgcn_s_barrier();   // ALL waves' DMAs landed before pool reuse

    // ---- epilogue: two 128-col passes; LDS tile [128][136], coalesced stores
    const int b     = m0 >> 11;
    const int lpos0 = m0 & (L_SEQ - 1);
#pragma unroll
    for (int t = 0; t < 2; ++t) {
        if ((wn >> 1) == t) {     // waves owning cols t*128..t*128+127
#pragma unroll
            for (int jf = 0; jf < 4; ++jf) {
                int nl = (wn & 1) * 64 + jf * 16 + l16;    // 0..127 in tile
                int nn = (bxp & 3) * 256 + t * 128 + nl;   // 0..1023 in weight
                float bval = bias[nn];
                int d  = nn & (HEADD - 1);
                float sgn = (d & 1) ? 1.0f : -1.0f;
                int i2 = d >> 1;
#pragma unroll
                for (int mf = 0; mf < 4; ++mf) {
#pragma unroll
                    for (int r = 0; r < 4; ++r) {
                        int ml = wm * 64 + mf * 16 + quad * 4 + r;
                        int lpos = (m0 + ml) & (L_SEQ - 1);
                        float v = acc[mf][jf][r] + bval;
                        if (sel < 2) {
                            float p = __shfl_xor(v, 1);   // partner (d^1)
                            float2 cs = *reinterpret_cast<const float2*>(&rope[(size_t)(lpos * 32 + i2) * 2]);
                            v = v * cs.x + sgn * cs.y * p;
                            if (sel == 0) v *= 0.18033688011112042f;  // log2e/8
                        }
                        pool[(sel < 2) ? (ml * 136 + nl) : (nl * 136 + ml)] = f2bf(v);
                    }
                }
            }
        }
        asm volatile("s_waitcnt lgkmcnt(0)" ::: "memory");
        __builtin_amdgcn_s_barrier();
        // store pass: 2048 int4 pieces / 512 threads = 4 each
#pragma unroll
        for (int i = 0; i < 4; ++i) {
            int g   = i * 512 + tid;
            int row = g >> 4;             // 0..127
            int c8  = (g & 15) * 8;       // 0..120
            int4 val = *reinterpret_cast<const int4*>(&pool[row * 136 + c8]);
            size_t addr;
            if (sel < 2) {                // row -> lpos, c8 -> n
                int n_g = (bxp & 3) * 256 + t * 128 + c8;
                int h = n_g >> 6, d = n_g & 63;
                addr = ((size_t)(b * NHEAD + h) * L_SEQ + (lpos0 + row)) * HEADD + d;
            } else {                      // row -> (h,d), c8 -> lpos
                int n_g = (bxp & 3) * 256 + t * 128 + row;
                int h = n_g >> 6, d = n_g & 63;
                addr = ((size_t)(b * NHEAD + h) * HEADD + d) * L_SEQ + lpos0 + c8;
            }
            *reinterpret_cast<int4*>(out + addr) = val;
        }
        asm volatile("s_waitcnt lgkmcnt(0)" ::: "memory");
        __builtin_amdgcn_s_barrier();
    }
}

// ---------------- flash attention (causal), S^T formulation -----------------
// Round 11: K/V ring-3 + counted vmcnt (proj's proven ledger). Stage tile kb+2
// at iter start; vmcnt(4) at iter end (oldest 4 retired => tile kb+1 landed);
// loads stay in flight across barriers instead of a full vmcnt(0) drain per
// iter. Per-wave staging regions disjoint; dummy stages target dead slots;
// per-half vmcnt(0) drain before buffer reuse. Compute bit-identical to r8.
__global__ __launch_bounds__(256) void attn_fwd(
    const unsigned short* __restrict__ Q,
    const unsigned short* __restrict__ K,
    const unsigned short* __restrict__ Vt,
    unsigned short* __restrict__ Oa)
{
    __shared__ unsigned short k_lds[3][64 * 64];   // 3 x 8KB
    __shared__ unsigned short v_lds[3][64 * 64];   // 3 x 8KB
    const int tid  = threadIdx.x;
    const int lane = tid & 63;
    const int w    = tid >> 6;
    const int quad = lane >> 4, l16 = lane & 15;
    const int pair = blockIdx.y;        // 0..7
    const int bh   = blockIdx.x;        // head -> XCD locality (T1)
    const size_t base = (size_t)bh * L_SEQ * HEADD;
    const int b = bh >> 4, h = bh & 15;

    const int srow  = lane >> 3;                 // 0..7
    const int sslot = lane & 7;
    const int ssw   = ((sslot ^ srow) << 3);     // pre-swizzled col offset (shorts)
    const unsigned short* Ksrc = K  + base + (size_t)(w * 8 + srow) * HEADD + ssw;
    const unsigned short* Vsrc = Vt + base + (size_t)(w * 8 + srow) * L_SEQ + ssw;
    const int d0 = (w * 8) * 64;
    const int d1 = (32 + w * 8) * 64;
    const int swr = (l16 & 7);                   // read-side row XOR key

    for (int half = 0; half < 2; ++half) {
        const int s = half ? (15 - pair) : pair;   // q super-block (128 rows)
        const int qrow0 = s * 128 + w * 16 + l16;
        const int qrow1 = qrow0 + 64;
        const int kbmax = 2 * s + 1;               // >= 1 always

        short8 qf0[2], qf1[2];
#pragma unroll
        for (int ks = 0; ks < 2; ++ks) {
            qf0[ks] = *reinterpret_cast<const short8*>(Q + base + (size_t)qrow0 * HEADD + ks * 32 + quad * 8);
            qf1[ks] = *reinterpret_cast<const short8*>(Q + base + (size_t)qrow1 * HEADD + ks * 32 + quad * 8);
        }

        f32x4 o0[4], o1[4];
#pragma unroll
        for (int nt = 0; nt < 4; ++nt) {
            o0[nt] = (f32x4){0.f, 0.f, 0.f, 0.f};
            o1[nt] = (f32x4){0.f, 0.f, 0.f, 0.f};
        }
        float lsum0 = 0.f, lsum1 = 0.f;

        // prologue: stage tiles 0,1 -> slots 0,1 (8 dma/thread)
#pragma unroll
        for (int p = 0; p < 2; ++p) {
            dma16(Ksrc + (size_t)(p * 64) * HEADD,        &k_lds[p][d0]);
            dma16(Ksrc + (size_t)(p * 64 + 32) * HEADD,   &k_lds[p][d1]);
            dma16(Vsrc + p * 64,                          &v_lds[p][d0]);
            dma16(Vsrc + p * 64 + 32 * L_SEQ,             &v_lds[p][d1]);
        }
        // outstanding <= 12 (4 qf + 8 dma); vmcnt(4) retires the oldest 8,
        // which always include all 4 tile-0 dmas (only tile-1 + qf can be newer)
        asm volatile("s_waitcnt vmcnt(4)" ::: "memory");
        __builtin_amdgcn_s_barrier();

        for (int kb = 0; kb <= kbmax; ++kb) {
            const int slot = kb % 3;
            const int ps   = (kb + 2) % 3;   // last read at iter kb-1, freed
            const int kn   = (kb + 2) <= kbmax ? (kb + 2) : 0;  // dummy wraps
            dma16(Ksrc + (size_t)(kn * 64) * HEADD,        &k_lds[ps][d0]);
            dma16(Ksrc + (size_t)(kn * 64 + 32) * HEADD,   &k_lds[ps][d1]);
            dma16(Vsrc + kn * 64,                          &v_lds[ps][d0]);
            dma16(Vsrc + kn * 64 + 32 * L_SEQ,             &v_lds[ps][d1]);

            f32x4 st0[4], st1[4];
#pragma unroll
            for (int nt = 0; nt < 4; ++nt) {
                st0[nt] = (f32x4){0.f, 0.f, 0.f, 0.f};
                st1[nt] = (f32x4){0.f, 0.f, 0.f, 0.f};
            }
            __builtin_amdgcn_s_setprio(1);
#pragma unroll
            for (int ks = 0; ks < 2; ++ks)
#pragma unroll
                for (int nt = 0; nt < 4; ++nt) {
                    short8 kf = *reinterpret_cast<const short8*>(
                        &k_lds[slot][(nt * 16 + l16) * 64 + (((ks * 4 + quad) ^ swr) << 3)]);
                    st0[nt] = __builtin_amdgcn_mfma_f32_16x16x32_bf16(kf, qf0[ks], st0[nt], 0, 0, 0);
                    st1[nt] = __builtin_amdgcn_mfma_f32_16x16x32_bf16(kf, qf1[ks], st1[nt], 0, 0, 0);
                }
            __builtin_amdgcn_s_setprio(0);

            if (kb >= 2 * s) {          // q0 diag (kb==2s) or fully-past (kb==2s+1)
#pragma unroll
                for (int nt = 0; nt < 4; ++nt)
#pragma unroll
                    for (int r = 0; r < 4; ++r) {
                        int seqcol = kb * 64 + nt * 16 + quad * 4 + r;
                        if (seqcol > qrow0) st0[nt][r] = -INFINITY;
                    }
            }
            if (kb == kbmax) {          // q1 diag
#pragma unroll
                for (int nt = 0; nt < 4; ++nt)
#pragma unroll
                    for (int r = 0; r < 4; ++r) {
                        int seqcol = kb * 64 + nt * 16 + quad * 4 + r;
                        if (seqcol > qrow1) st1[nt][r] = -INFINITY;
                    }
            }

            short4v pfrag0[4], pfrag1[4];
#pragma unroll
            for (int nt = 0; nt < 4; ++nt) {
                float p0 = __builtin_amdgcn_exp2f(st0[nt][0]);
                float p1 = __builtin_amdgcn_exp2f(st0[nt][1]);
                float p2 = __builtin_amdgcn_exp2f(st0[nt][2]);
                float p3 = __builtin_amdgcn_exp2f(st0[nt][3]);
                lsum0 += (p0 + p1) + (p2 + p3);
                unsigned u0 = __float_as_uint(p0) + 0x8000u;
                unsigned u1 = __float_as_uint(p1) + 0x8000u;
                unsigned u2 = __float_as_uint(p2) + 0x8000u;
                unsigned u3 = __float_as_uint(p3) + 0x8000u;
                union { unsigned u[2]; short4v v; } pk;
                pk.u[0] = (u0 >> 16) | (u1 & 0xffff0000u);
                pk.u[1] = (u2 >> 16) | (u3 & 0xffff0000u);
                pfrag0[nt] = pk.v;

                float q0e = __builtin_amdgcn_exp2f(st1[nt][0]);
                float q1e = __builtin_amdgcn_exp2f(st1[nt][1]);
                float q2e = __builtin_amdgcn_exp2f(st1[nt][2]);
                float q3e = __builtin_amdgcn_exp2f(st1[nt][3]);
                lsum1 += (q0e + q1e) + (q2e + q3e);
                unsigned v0 = __float_as_uint(q0e) + 0x8000u;
                unsigned v1 = __float_as_uint(q1e) + 0x8000u;
                unsigned v2 = __float_as_uint(q2e) + 0x8000u;
                unsigned v3 = __float_as_uint(q3e) + 0x8000u;
                union { unsigned u[2]; short4v v; } pk1;
                pk1.u[0] = (v0 >> 16) | (v1 & 0xffff0000u);
                pk1.u[1] = (v2 >> 16) | (v3 & 0xffff0000u);
                pfrag1[nt] = pk1.v;
            }

            __builtin_amdgcn_s_setprio(1);
#pragma unroll
            for (int c = 0; c < 4; ++c)
#pragma unroll
                for (int nt2 = 0; nt2 < 4; ++nt2) {
                    short4v vf = *reinterpret_cast<const short4v*>(
                        &v_lds[slot][(nt2 * 16 + l16) * 64 +
                                     (((c * 2 + (quad >> 1)) ^ swr) << 3) + ((quad & 1) << 2)]);
                    o0[nt2] = __builtin_amdgcn_mfma_f32_16x16x16bf16_1k(pfrag0[c], vf, o0[nt2], 0, 0, 0);
                    o1[nt2] = __builtin_amdgcn_mfma_f32_16x16x16bf16_1k(pfrag1[c], vf, o1[nt2], 0, 0, 0);
                }
            __builtin_amdgcn_s_setprio(0);

            // boundary: outstanding <= 8 (tiles kb+1, kb+2); vmcnt(4) => kb+1
            // landed; barrier closes WAR on slot (kb+2)%3 for next iteration.
            asm volatile("s_waitcnt vmcnt(4)" ::: "memory");
            __builtin_amdgcn_s_barrier();
        }
        asm volatile("s_waitcnt vmcnt(0)" ::: "memory");  // retire dummies
        __builtin_amdgcn_s_barrier();                      // before buffer reuse

        // ---- epilogue: row-sum reduce + normalized store, both halves
        lsum0 += __shfl_xor(lsum0, 16);
        lsum0 += __shfl_xor(lsum0, 32);
        lsum1 += __shfl_xor(lsum1, 16);
        lsum1 += __shfl_xor(lsum1, 32);
        float rs0[4], rs1[4];
#pragma unroll
        for (int r = 0; r < 4; ++r) {
            rs0[r] = __shfl(lsum0, quad * 4 + r);
            rs1[r] = __shfl(lsum1, quad * 4 + r);
        }
#pragma unroll
        for (int r = 0; r < 4; ++r) {
            float inv0 = 1.0f / rs0[r];
            float inv1 = 1.0f / rs1[r];
            int lg0 = s * 128 + w * 16 + quad * 4 + r;
            int lg1 = lg0 + 64;
#pragma unroll
            for (int nt = 0; nt < 4; ++nt) {
                int d = nt * 16 + l16;
                Oa[(size_t)(b * L_SEQ + lg0) * DMODEL + h * HEADD + d] = f2bf(o0[nt][r] * inv0);
                Oa[(size_t)(b * L_SEQ + lg1) * DMODEL + h * HEADD + d] = f2bf(o1[nt][r] * inv1);
            }
        }
    }
}

// ---------------- output projection: fp32 out = A @ Wo^T + bo ---------------
// Ring-3 / 1-barrier structure; L2-topology swizzle (by-grouped XCD).
__global__ __launch_bounds__(256) void out_gemm(
    const unsigned short* __restrict__ X,
    const unsigned short* __restrict__ W,
    const float* __restrict__ bias,
    float* __restrict__ out)
{
    __shared__ unsigned short a_lds[3][128 * BKP];
    __shared__ unsigned short b_lds[3][128 * BKP];
    const int tid  = threadIdx.x;
    const int lane = tid & 63;
    const int w    = tid >> 6;
    const int wm   = w & 1, wn = w >> 1;
    const int quad = lane >> 4, l16 = lane & 15;

    // L2-topology swizzle: xcd owns by in [xcd*8, xcd*8+8); bx-major inside
    const int orig = blockIdx.y * 8 + blockIdx.x;
    const int xcd  = orig & 7;
    const int k    = orig >> 3;         // 0..63
    const int m0   = (xcd * 8 + (k & 7)) * 128;
    const int n0   = (k >> 3) * 128;

    const int st_row = lane >> 2;
    const int st_col = (((lane & 3) ^ ((lane >> 3) & 3)) << 3);
    const int rd = ((quad ^ ((l16 >> 1) & 3)) << 3);

    f32x4 acc[4][4];
#pragma unroll
    for (int i = 0; i < 4; ++i)
#pragma unroll
        for (int j = 0; j < 4; ++j) acc[i][j] = (f32x4){0.f, 0.f, 0.f, 0.f};

    const unsigned short* Xs = X + (size_t)(m0 + w * 32 + st_row) * DMODEL + st_col;
    const unsigned short* Ws = W + (size_t)(n0 + w * 32 + st_row) * DMODEL + st_col;
    const int ldsA0 = (w * 32) * BKP, ldsA1 = (w * 32 + 16) * BKP;

#pragma unroll
    for (int p = 0; p < 2; ++p) {
        const int kk = p * BKP;
        dma16(Xs + kk,               &a_lds[p][ldsA0]);
        dma16(Xs + 16 * DMODEL + kk, &a_lds[p][ldsA1]);
        dma16(Ws + kk,               &b_lds[p][ldsA0]);
        dma16(Ws + 16 * DMODEL + kk, &b_lds[p][ldsA1]);
    }
    asm volatile("s_waitcnt vmcnt(4)" ::: "memory");
    __builtin_amdgcn_s_barrier();

    for (int kt = 0; kt < 32; ++kt) {
        const int slot = kt % 3;
        const int ps   = (kt + 2) % 3;
        const int kk   = ((kt + 2) & 31) * BKP;

        dma16(Xs + kk,               &a_lds[ps][ldsA0]);
        dma16(Xs + 16 * DMODEL + kk, &a_lds[ps][ldsA1]);
        dma16(Ws + kk,               &b_lds[ps][ldsA0]);
        dma16(Ws + 16 * DMODEL + kk, &b_lds[ps][ldsA1]);

        short8 af[4], bf[4];
#pragma unroll
        for (int i = 0; i < 4; ++i)
            af[i] = *reinterpret_cast<const short8*>(
                &a_lds[slot][(wm * 64 + i * 16 + l16) * BKP + rd]);
#pragma unroll
        for (int j = 0; j < 4; ++j)
            bf[j] = *reinterpret_cast<const short8*>(
                &b_lds[slot][(wn * 64 + j * 16 + l16) * BKP + rd]);
        asm volatile("s_waitcnt lgkmcnt(0)" ::: "memory");
        __builtin_amdgcn_sched_barrier(0);
        __builtin_amdgcn_s_setprio(1);
#pragma unroll
        for (int i = 0; i < 4; ++i)
#pragma unroll
            for (int j = 0; j < 4; ++j)
                acc[i][j] = __builtin_amdgcn_mfma_f32_16x16x32_bf16(af[i], bf[j], acc[i][j], 0, 0, 0);
        __builtin_amdgcn_s_setprio(0);
        asm volatile("s_waitcnt vmcnt(4)" ::: "memory");
        __builtin_amdgcn_s_barrier();
    }
    asm volatile("s_waitcnt vmcnt(0)" ::: "memory");

#pragma unroll
    for (int nt = 0; nt < 4; ++nt) {
        int n_g = n0 + wn * 64 + nt * 16 + l16;
        float bv = bias[n_g];
#pragma unroll
        for (int mt = 0; mt < 4; ++mt)
#pragma unroll
            for (int r = 0; r < 4; ++r) {
                int m_g = m0 + wm * 64 + mt * 16 + quad * 4 + r;
                out[(size_t)m_g * DMODEL + n_g] = acc[mt][nt][r] + bv;
            }
    }
}

extern "C" void kernel_launch(void* const* d_in, const int* in_sizes, int n_in,
                              void* d_out, int out_size, void* d_ws, size_t ws_size,
                              hipStream_t stream) {
    const float* query = (const float*)d_in[0];
    const float* Wq = (const float*)d_in[1];
    const float* bq = (const float*)d_in[2];
    const float* Wk = (const float*)d_in[3];
    const float* bk = (const float*)d_in[4];
    const float* Wv = (const float*)d_in[5];
    const float* bv = (const float*)d_in[6];
    const float* Wo = (const float*)d_in[7];
    const float* bo = (const float*)d_in[8];
    float* out = (float*)d_out;

    unsigned short* ws  = (unsigned short*)d_ws;
    unsigned short* xb  = ws;                       // 8192*1024
    unsigned short* wqb = xb  + (size_t)8388608;    // 1024*1024 each, CONTIGUOUS wq|wk|wv|wo
    unsigned short* wkb = wqb + 1048576;
    unsigned short* wvb = wkb + 1048576;
    unsigned short* wob = wvb + 1048576;
    unsigned short* Qb  = wob + 1048576;            // [bh][l][d]
    unsigned short* Kb  = Qb  + 8388608;
    unsigned short* Vr  = Kb  + 8388608;            // [bh][d][l] (written directly by proj)
    unsigned short* Ab  = Vr  + 8388608;            // [b][l][h*d]
    float* rope = (float*)(Ab + 8388608);           // 2048*32 float2 = 512 KB

    (void)wkb; (void)wvb;

    // fused prep: X cvt + weight cvt + rope table (one dispatch, 12545 blocks)
    prep<<<12545, 256, 0, stream>>>(query, Wq, Wk, Wv, Wo, xb, wqb, rope);

    // fused QKV GEMM: M=8192 x N=3072, 128x256 tiles -> grid (12, 64) = 768 blocks
    proj_qkv<<<dim3(12, 64), 512, 0, stream>>>(xb, wqb, bq, bk, bv, rope, Qb, Kb, Vr);
    // grid (bh, pair): 128 q-rows/block; s=pair & 15-pair -> 36 tile-units each
    attn_fwd<<<dim3(64, 8), 256, 0, stream>>>(Qb, Kb, Vr, Ab);
    out_gemm<<<dim3(8, 64), 256, 0, stream>>>(Ab, wob, bo, out);
}

// Round 12
// 261.874 us; speedup vs baseline: 1.0602x; 1.0218x over previous
//
#include <hip/hip_runtime.h>
#include <hip/hip_bf16.h>
#include <math.h>

#define L_SEQ  2048
#define DMODEL 1024
#define NHEAD  16
#define HEADD  64

typedef __attribute__((ext_vector_type(8))) short short8;
typedef __attribute__((ext_vector_type(4))) short short4v;
typedef __attribute__((ext_vector_type(4))) float f32x4;

// RNE float -> bf16 bits
static __device__ __forceinline__ unsigned short f2bf(float f) {
    unsigned int u = __float_as_uint(f);
    unsigned int r = (u + 0x7fffu + ((u >> 16) & 1u)) >> 16;
    return (unsigned short)r;
}

static __device__ __forceinline__ void dma16(const unsigned short* g, unsigned short* l) {
    __builtin_amdgcn_global_load_lds((const __attribute__((address_space(1))) void*)g,
                                     (__attribute__((address_space(3))) void*)l, 16, 0, 0);
}

// ---------------- fused prep: X->bf16, 4 weights->bf16, RoPE table ----------
__global__ __launch_bounds__(256) void prep(
    const float* __restrict__ query,
    const float* __restrict__ Wq, const float* __restrict__ Wk,
    const float* __restrict__ Wv, const float* __restrict__ Wo,
    unsigned short* __restrict__ xb, unsigned short* __restrict__ wdst,
    float* __restrict__ rope)
{
    int gid = blockIdx.x * 256 + threadIdx.x;
    if (gid < 2097152) {
        float4 v = reinterpret_cast<const float4*>(query)[gid];
        ushort4 o;
        o.x = f2bf(v.x); o.y = f2bf(v.y); o.z = f2bf(v.z); o.w = f2bf(v.w);
        reinterpret_cast<ushort4*>(xb)[gid] = o;
    } else if (gid < 2097152 + 1048576) {
        int i = gid - 2097152;
        int which = i >> 18;                  // 262144 groups per weight
        const float* src = which == 0 ? Wq : which == 1 ? Wk : which == 2 ? Wv : Wo;
        float4 v = reinterpret_cast<const float4*>(src)[i & 262143];
        ushort4 o;
        o.x = f2bf(v.x); o.y = f2bf(v.y); o.z = f2bf(v.z); o.w = f2bf(v.w);
        reinterpret_cast<ushort4*>(wdst)[i] = o;
    } else if (gid < 2097152 + 1048576 + 65536) {
        int i = gid - (2097152 + 1048576);
        int lpos = i >> 5, i2 = i & 31;
        float inv_f = expf(-0.28782313662425574f * (float)i2);  // 10000^(-i2/32)
        float ang = (float)lpos * inv_f;
        rope[2 * i]     = cosf(ang);
        rope[2 * i + 1] = sinf(ang);
    }
}

// ---------------- fused QKV projection -------------------------------------
// ROUND-10 EXACT (92 us): 128x256 tile, 8 waves (2Mx4N), BK=32, ring-3 LDS
// (72KB -> 2 blocks/CU), counted vmcnt(3), 2 barriers/iter, L2-topology
// swizzle, LDS-staged coalesced epilogue.
#define BKP 32

__global__ __launch_bounds__(512, 4) void proj_qkv(
    const unsigned short* __restrict__ X,
    const unsigned short* __restrict__ Wqkv,
    const float* __restrict__ bq_,
    const float* __restrict__ bk_,
    const float* __restrict__ bv_,
    const float* __restrict__ rope,
    unsigned short* __restrict__ Qb,
    unsigned short* __restrict__ Kb,
    unsigned short* __restrict__ Vr)
{
    // 72 KB pool: A ring 3x4096 shorts | B ring 3x8192; epilogue tile 128x136
    __shared__ unsigned short pool[36864];
    unsigned short* a_ring = pool;            // slot s: + s*4096
    unsigned short* b_ring = pool + 12288;    // slot s: + s*8192

    const int tid  = threadIdx.x;
    const int lane = tid & 63;
    const int w    = tid >> 6;          // 0..7
    const int wm   = w & 1, wn = w >> 1;     // 2M x 4N
    const int quad = lane >> 4, l16 = lane & 15;

    // L2-topology swizzle: xcd = orig&7 owns by in [xcd*8, xcd*8+8).
    const int orig = blockIdx.y * 12 + blockIdx.x;
    const int xcd  = orig & 7;
    const int k    = orig >> 3;         // 0..95
    const int by   = xcd * 8 + (k & 7); // 0..63
    const int bxp  = k >> 3;            // 0..11 (n-pair index)
    const int m0   = by * 128;
    const int n0   = bxp * 256;

    const int sel = bxp >> 2;           // wave-uniform: 0=Q 1=K 2=V
    const float* bias   = sel == 0 ? bq_ : (sel == 1 ? bk_ : bv_);
    unsigned short* out = sel == 0 ? Qb  : (sel == 1 ? Kb  : Vr);

    const int st_row = lane >> 2;                                   // 0..15
    const int st_col = (((lane & 3) ^ ((lane >> 3) & 3)) << 3);     // shorts
    const int rd = ((quad ^ ((l16 >> 1) & 3)) << 3);

    f32x4 acc[4][4];
#pragma unroll
    for (int i = 0; i < 4; ++i)
#pragma unroll
        for (int j = 0; j < 4; ++j) acc[i][j] = (f32x4){0.f, 0.f, 0.f, 0.f};

    // staging: A 128 rows/8 waves = 16 rows = 1 dma; B 256/8 = 32 rows = 2 dma
    const unsigned short* Xs = X    + (size_t)(m0 + w * 16 + st_row) * DMODEL + st_col;
    const unsigned short* Ws = Wqkv + (size_t)(n0 + w * 32 + st_row) * DMODEL + st_col;
    const int ldsA  = (w * 16) * BKP;
    const int ldsB0 = (w * 32) * BKP, ldsB1 = (w * 32 + 16) * BKP;

    // ---- prologue: stage tiles 0,1 into slots 0,1 (3 dma/wave each)
#pragma unroll
    for (int p = 0; p < 2; ++p) {
        const int kk = p * BKP;
        dma16(Xs + kk,               a_ring + p * 4096 + ldsA);
        dma16(Ws + kk,               b_ring + p * 8192 + ldsB0);
        dma16(Ws + 16 * DMODEL + kk, b_ring + p * 8192 + ldsB1);
    }
    asm volatile("s_waitcnt vmcnt(3)" ::: "memory");   // tile 0 fully landed
    __builtin_amdgcn_s_barrier();

    for (int kt = 0; kt < 32; ++kt) {
        const int sA = (kt % 3) * 4096;
        const int sB = (kt % 3) * 8192;
        const int pA = ((kt + 2) % 3) * 4096;    // freed at end of iter kt-1
        const int pB = ((kt + 2) % 3) * 8192;
        const int kk = ((kt + 2) & 31) * BKP;    // wrap keeps ledger uniform

        short8 af[4], bf[4];
#pragma unroll
        for (int i = 0; i < 4; ++i)
            af[i] = *reinterpret_cast<const short8*>(
                &a_ring[sA + (wm * 64 + i * 16 + l16) * BKP + rd]);
#pragma unroll
        for (int j = 0; j < 4; ++j)
            bf[j] = *reinterpret_cast<const short8*>(
                &b_ring[sB + (wn * 64 + j * 16 + l16) * BKP + rd]);
        dma16(Xs + kk,               a_ring + pA + ldsA);
        dma16(Ws + kk,               b_ring + pB + ldsB0);
        dma16(Ws + 16 * DMODEL + kk, b_ring + pB + ldsB1);
        __builtin_amdgcn_s_barrier();
        asm volatile("s_waitcnt lgkmcnt(0)" ::: "memory");
        __builtin_amdgcn_sched_barrier(0);
        __builtin_amdgcn_s_setprio(1);
#pragma unroll
        for (int i = 0; i < 4; ++i)
#pragma unroll
            for (int j = 0; j < 4; ++j)
                acc[i][j] = __builtin_amdgcn_mfma_f32_16x16x32_bf16(af[i], bf[j], acc[i][j], 0, 0, 0);
        __builtin_amdgcn_s_setprio(0);
        // boundary: in flight <= 6 (tiles kt+1, kt+2); vmcnt(3) => kt+1 landed
        asm volatile("s_waitcnt vmcnt(3)" ::: "memory");
        __builtin_amdgcn_s_barrier();
    }
    asm volatile("s_waitcnt vmcnt(0)" ::: "memory");   // retire wrapped dummies
    __builtin_amdgcn_s_barrier();   // ALL waves' DMAs landed before pool reuse

    // ---- epilogue: two 128-col passes; LDS tile [128][136], coalesced stores
    const int b     = m0 >> 11;
    const int lpos0 = m0 & (L_SEQ - 1);
#pragma unroll
    for (int t = 0; t < 2; ++t) {
        if ((wn >> 1) == t) {     // waves owning cols t*128..t*128+127
#pragma unroll
            for (int jf = 0; jf < 4; ++jf) {
                int nl = (wn & 1) * 64 + jf * 16 + l16;    // 0..127 in tile
                int nn = (bxp & 3) * 256 + t * 128 + nl;   // 0..1023 in weight
                float bval = bias[nn];
                int d  = nn & (HEADD - 1);
                float sgn = (d & 1) ? 1.0f : -1.0f;
                int i2 = d >> 1;
#pragma unroll
                for (int mf = 0; mf < 4; ++mf) {
#pragma unroll
                    for (int r = 0; r < 4; ++r) {
                        int ml = wm * 64 + mf * 16 + quad * 4 + r;
                        int lpos = (m0 + ml) & (L_SEQ - 1);
                        float v = acc[mf][jf][r] + bval;
                        if (sel < 2) {
                            float p = __shfl_xor(v, 1);   // partner (d^1)
                            float2 cs = *reinterpret_cast<const float2*>(&rope[(size_t)(lpos * 32 + i2) * 2]);
                            v = v * cs.x + sgn * cs.y * p;
                            if (sel == 0) v *= 0.18033688011112042f;  // log2e/8
                        }
                        pool[(sel < 2) ? (ml * 136 + nl) : (nl * 136 + ml)] = f2bf(v);
                    }
                }
            }
        }
        asm volatile("s_waitcnt lgkmcnt(0)" ::: "memory");
        __builtin_amdgcn_s_barrier();
        // store pass: 2048 int4 pieces / 512 threads = 4 each
#pragma unroll
        for (int i = 0; i < 4; ++i) {
            int g   = i * 512 + tid;
            int row = g >> 4;             // 0..127
            int c8  = (g & 15) * 8;       // 0..120
            int4 val = *reinterpret_cast<const int4*>(&pool[row * 136 + c8]);
            size_t addr;
            if (sel < 2) {                // row -> lpos, c8 -> n
                int n_g = (bxp & 3) * 256 + t * 128 + c8;
                int h = n_g >> 6, d = n_g & 63;
                addr = ((size_t)(b * NHEAD + h) * L_SEQ + (lpos0 + row)) * HEADD + d;
            } else {                      // row -> (h,d), c8 -> lpos
                int n_g = (bxp & 3) * 256 + t * 128 + row;
                int h = n_g >> 6, d = n_g & 63;
                addr = ((size_t)(b * NHEAD + h) * HEADD + d) * L_SEQ + lpos0 + c8;
            }
            *reinterpret_cast<int4*>(out + addr) = val;
        }
        asm volatile("s_waitcnt lgkmcnt(0)" ::: "memory");
        __builtin_amdgcn_s_barrier();
    }
}

// ---------------- flash attention (causal), S^T formulation -----------------
// ROUND-11 EXACT: 128 q-rows/block, K/V ring-3 + counted vmcnt(4), loads in
// flight across barriers; per-half vmcnt(0) drain before buffer reuse.
__global__ __launch_bounds__(256) void attn_fwd(
    const unsigned short* __restrict__ Q,
    const unsigned short* __restrict__ K,
    const unsigned short* __restrict__ Vt,
    unsigned short* __restrict__ Oa)
{
    __shared__ unsigned short k_lds[3][64 * 64];   // 3 x 8KB
    __shared__ unsigned short v_lds[3][64 * 64];   // 3 x 8KB
    const int tid  = threadIdx.x;
    const int lane = tid & 63;
    const int w    = tid >> 6;
    const int quad = lane >> 4, l16 = lane & 15;
    const int pair = blockIdx.y;        // 0..7
    const int bh   = blockIdx.x;        // head -> XCD locality (T1)
    const size_t base = (size_t)bh * L_SEQ * HEADD;
    const int b = bh >> 4, h = bh & 15;

    const int srow  = lane >> 3;                 // 0..7
    const int sslot = lane & 7;
    const int ssw   = ((sslot ^ srow) << 3);     // pre-swizzled col offset (shorts)
    const unsigned short* Ksrc = K  + base + (size_t)(w * 8 + srow) * HEADD + ssw;
    const unsigned short* Vsrc = Vt + base + (size_t)(w * 8 + srow) * L_SEQ + ssw;
    const int d0 = (w * 8) * 64;
    const int d1 = (32 + w * 8) * 64;
    const int swr = (l16 & 7);                   // read-side row XOR key

    for (int half = 0; half < 2; ++half) {
        const int s = half ? (15 - pair) : pair;   // q super-block (128 rows)
        const int qrow0 = s * 128 + w * 16 + l16;
        const int qrow1 = qrow0 + 64;
        const int kbmax = 2 * s + 1;               // >= 1 always

        short8 qf0[2], qf1[2];
#pragma unroll
        for (int ks = 0; ks < 2; ++ks) {
            qf0[ks] = *reinterpret_cast<const short8*>(Q + base + (size_t)qrow0 * HEADD + ks * 32 + quad * 8);
            qf1[ks] = *reinterpret_cast<const short8*>(Q + base + (size_t)qrow1 * HEADD + ks * 32 + quad * 8);
        }

        f32x4 o0[4], o1[4];
#pragma unroll
        for (int nt = 0; nt < 4; ++nt) {
            o0[nt] = (f32x4){0.f, 0.f, 0.f, 0.f};
            o1[nt] = (f32x4){0.f, 0.f, 0.f, 0.f};
        }
        float lsum0 = 0.f, lsum1 = 0.f;

        // prologue: stage tiles 0,1 -> slots 0,1 (8 dma/thread)
#pragma unroll
        for (int p = 0; p < 2; ++p) {
            dma16(Ksrc + (size_t)(p * 64) * HEADD,        &k_lds[p][d0]);
            dma16(Ksrc + (size_t)(p * 64 + 32) * HEADD,   &k_lds[p][d1]);
            dma16(Vsrc + p * 64,                          &v_lds[p][d0]);
            dma16(Vsrc + p * 64 + 32 * L_SEQ,             &v_lds[p][d1]);
        }
        // outstanding <= 12 (4 qf + 8 dma); vmcnt(4) retires the oldest 8,
        // which always include all 4 tile-0 dmas
        asm volatile("s_waitcnt vmcnt(4)" ::: "memory");
        __builtin_amdgcn_s_barrier();

        for (int kb = 0; kb <= kbmax; ++kb) {
            const int slot = kb % 3;
            const int ps   = (kb + 2) % 3;   // last read at iter kb-1, freed
            const int kn   = (kb + 2) <= kbmax ? (kb + 2) : 0;  // dummy wraps
            dma16(Ksrc + (size_t)(kn * 64) * HEADD,        &k_lds[ps][d0]);
            dma16(Ksrc + (size_t)(kn * 64 + 32) * HEADD,   &k_lds[ps][d1]);
            dma16(Vsrc + kn * 64,                          &v_lds[ps][d0]);
            dma16(Vsrc + kn * 64 + 32 * L_SEQ,             &v_lds[ps][d1]);

            f32x4 st0[4], st1[4];
#pragma unroll
            for (int nt = 0; nt < 4; ++nt) {
                st0[nt] = (f32x4){0.f, 0.f, 0.f, 0.f};
                st1[nt] = (f32x4){0.f, 0.f, 0.f, 0.f};
            }
            __builtin_amdgcn_s_setprio(1);
#pragma unroll
            for (int ks = 0; ks < 2; ++ks)
#pragma unroll
                for (int nt = 0; nt < 4; ++nt) {
                    short8 kf = *reinterpret_cast<const short8*>(
                        &k_lds[slot][(nt * 16 + l16) * 64 + (((ks * 4 + quad) ^ swr) << 3)]);
                    st0[nt] = __builtin_amdgcn_mfma_f32_16x16x32_bf16(kf, qf0[ks], st0[nt], 0, 0, 0);
                    st1[nt] = __builtin_amdgcn_mfma_f32_16x16x32_bf16(kf, qf1[ks], st1[nt], 0, 0, 0);
                }
            __builtin_amdgcn_s_setprio(0);

            if (kb >= 2 * s) {          // q0 diag (kb==2s) or fully-past (kb==2s+1)
#pragma unroll
                for (int nt = 0; nt < 4; ++nt)
#pragma unroll
                    for (int r = 0; r < 4; ++r) {
                        int seqcol = kb * 64 + nt * 16 + quad * 4 + r;
                        if (seqcol > qrow0) st0[nt][r] = -INFINITY;
                    }
            }
            if (kb == kbmax) {          // q1 diag
#pragma unroll
                for (int nt = 0; nt < 4; ++nt)
#pragma unroll
                    for (int r = 0; r < 4; ++r) {
                        int seqcol = kb * 64 + nt * 16 + quad * 4 + r;
                        if (seqcol > qrow1) st1[nt][r] = -INFINITY;
                    }
            }

            short4v pfrag0[4], pfrag1[4];
#pragma unroll
            for (int nt = 0; nt < 4; ++nt) {
                float p0 = __builtin_amdgcn_exp2f(st0[nt][0]);
                float p1 = __builtin_amdgcn_exp2f(st0[nt][1]);
                float p2 = __builtin_amdgcn_exp2f(st0[nt][2]);
                float p3 = __builtin_amdgcn_exp2f(st0[nt][3]);
                lsum0 += (p0 + p1) + (p2 + p3);
                unsigned u0 = __float_as_uint(p0) + 0x8000u;
                unsigned u1 = __float_as_uint(p1) + 0x8000u;
                unsigned u2 = __float_as_uint(p2) + 0x8000u;
                unsigned u3 = __float_as_uint(p3) + 0x8000u;
                union { unsigned u[2]; short4v v; } pk;
                pk.u[0] = (u0 >> 16) | (u1 & 0xffff0000u);
                pk.u[1] = (u2 >> 16) | (u3 & 0xffff0000u);
                pfrag0[nt] = pk.v;

                float q0e = __builtin_amdgcn_exp2f(st1[nt][0]);
                float q1e = __builtin_amdgcn_exp2f(st1[nt][1]);
                float q2e = __builtin_amdgcn_exp2f(st1[nt][2]);
                float q3e = __builtin_amdgcn_exp2f(st1[nt][3]);
                lsum1 += (q0e + q1e) + (q2e + q3e);
                unsigned v0 = __float_as_uint(q0e) + 0x8000u;
                unsigned v1 = __float_as_uint(q1e) + 0x8000u;
                unsigned v2 = __float_as_uint(q2e) + 0x8000u;
                unsigned v3 = __float_as_uint(q3e) + 0x8000u;
                union { unsigned u[2]; short4v v; } pk1;
                pk1.u[0] = (v0 >> 16) | (v1 & 0xffff0000u);
                pk1.u[1] = (v2 >> 16) | (v3 & 0xffff0000u);
                pfrag1[nt] = pk1.v;
            }

            __builtin_amdgcn_s_setprio(1);
#pragma unroll
            for (int c = 0; c < 4; ++c)
#pragma unroll
                for (int nt2 = 0; nt2 < 4; ++nt2) {
                    short4v vf = *reinterpret_cast<const short4v*>(
                        &v_lds[slot][(nt2 * 16 + l16) * 64 +
                                     (((c * 2 + (quad >> 1)) ^ swr) << 3) + ((quad & 1) << 2)]);
                    o0[nt2] = __builtin_amdgcn_mfma_f32_16x16x16bf16_1k(pfrag0[c], vf, o0[nt2], 0, 0, 0);
                    o1[nt2] = __builtin_amdgcn_mfma_f32_16x16x16bf16_1k(pfrag1[c], vf, o1[nt2], 0, 0, 0);
                }
            __builtin_amdgcn_s_setprio(0);

            // boundary: outstanding <= 8 (tiles kb+1, kb+2); vmcnt(4) => kb+1
            // landed; barrier closes WAR on slot (kb+2)%3 for next iteration.
            asm volatile("s_waitcnt vmcnt(4)" ::: "memory");
            __builtin_amdgcn_s_barrier();
        }
        asm volatile("s_waitcnt vmcnt(0)" ::: "memory");  // retire dummies
        __builtin_amdgcn_s_barrier();                      // before buffer reuse

        // ---- epilogue: row-sum reduce + normalized store, both halves
        lsum0 += __shfl_xor(lsum0, 16);
        lsum0 += __shfl_xor(lsum0, 32);
        lsum1 += __shfl_xor(lsum1, 16);
        lsum1 += __shfl_xor(lsum1, 32);
        float rs0[4], rs1[4];
#pragma unroll
        for (int r = 0; r < 4; ++r) {
            rs0[r] = __shfl(lsum0, quad * 4 + r);
            rs1[r] = __shfl(lsum1, quad * 4 + r);
        }
#pragma unroll
        for (int r = 0; r < 4; ++r) {
            float inv0 = 1.0f / rs0[r];
            float inv1 = 1.0f / rs1[r];
            int lg0 = s * 128 + w * 16 + quad * 4 + r;
            int lg1 = lg0 + 64;
#pragma unroll
            for (int nt = 0; nt < 4; ++nt) {
                int d = nt * 16 + l16;
                Oa[(size_t)(b * L_SEQ + lg0) * DMODEL + h * HEADD + d] = f2bf(o0[nt][r] * inv0);
                Oa[(size_t)(b * L_SEQ + lg1) * DMODEL + h * HEADD + d] = f2bf(o1[nt][r] * inv1);
            }
        }
    }
}

// ---------------- output projection: fp32 out = A @ Wo^T + bo ---------------
// Round 12: ported to the proven 128x256 / 8-wave / ring-3 / counted-vmcnt(3)
// structure (proj's K-loop verbatim). Grid (4,64) = 256 blocks, bijective
// L2-topology swizzle. Epilogue: direct fp32 stores (bit-identical addresses).
__global__ __launch_bounds__(512, 4) void out_gemm(
    const unsigned short* __restrict__ X,
    const unsigned short* __restrict__ W,
    const float* __restrict__ bias,
    float* __restrict__ out)
{
    __shared__ unsigned short pool[36864];    // A ring 3x4096 | B ring 3x8192
    unsigned short* a_ring = pool;
    unsigned short* b_ring = pool + 12288;

    const int tid  = threadIdx.x;
    const int lane = tid & 63;
    const int w    = tid >> 6;          // 0..7
    const int wm   = w & 1, wn = w >> 1;     // 2M x 4N
    const int quad = lane >> 4, l16 = lane & 15;

    // L2-topology swizzle: nwg = 256, 256 % 8 == 0; xcd owns 8 m-panels
    const int orig = blockIdx.y * 4 + blockIdx.x;
    const int xcd  = orig & 7;
    const int k    = orig >> 3;         // 0..31
    const int m0   = (xcd * 8 + (k & 7)) * 128;
    const int bxp  = k >> 3;            // 0..3
    const int n0   = bxp * 256;

    const int st_row = lane >> 2;
    const int st_col = (((lane & 3) ^ ((lane >> 3) & 3)) << 3);
    const int rd = ((quad ^ ((l16 >> 1) & 3)) << 3);

    f32x4 acc[4][4];
#pragma unroll
    for (int i = 0; i < 4; ++i)
#pragma unroll
        for (int j = 0; j < 4; ++j) acc[i][j] = (f32x4){0.f, 0.f, 0.f, 0.f};

    const unsigned short* Xs = X + (size_t)(m0 + w * 16 + st_row) * DMODEL + st_col;
    const unsigned short* Ws = W + (size_t)(n0 + w * 32 + st_row) * DMODEL + st_col;
    const int ldsA  = (w * 16) * BKP;
    const int ldsB0 = (w * 32) * BKP, ldsB1 = (w * 32 + 16) * BKP;

#pragma unroll
    for (int p = 0; p < 2; ++p) {
        const int kk = p * BKP;
        dma16(Xs + kk,               a_ring + p * 4096 + ldsA);
        dma16(Ws + kk,               b_ring + p * 8192 + ldsB0);
        dma16(Ws + 16 * DMODEL + kk, b_ring + p * 8192 + ldsB1);
    }
    asm volatile("s_waitcnt vmcnt(3)" ::: "memory");
    __builtin_amdgcn_s_barrier();

    for (int kt = 0; kt < 32; ++kt) {
        const int sA = (kt % 3) * 4096;
        const int sB = (kt % 3) * 8192;
        const int pA = ((kt + 2) % 3) * 4096;
        const int pB = ((kt + 2) % 3) * 8192;
        const int kk = ((kt + 2) & 31) * BKP;

        short8 af[4], bf[4];
#pragma unroll
        for (int i = 0; i < 4; ++i)
            af[i] = *reinterpret_cast<const short8*>(
                &a_ring[sA + (wm * 64 + i * 16 + l16) * BKP + rd]);
#pragma unroll
        for (int j = 0; j < 4; ++j)
            bf[j] = *reinterpret_cast<const short8*>(
                &b_ring[sB + (wn * 64 + j * 16 + l16) * BKP + rd]);
        dma16(Xs + kk,               a_ring + pA + ldsA);
        dma16(Ws + kk,               b_ring + pB + ldsB0);
        dma16(Ws + 16 * DMODEL + kk, b_ring + pB + ldsB1);
        __builtin_amdgcn_s_barrier();
        asm volatile("s_waitcnt lgkmcnt(0)" ::: "memory");
        __builtin_amdgcn_sched_barrier(0);
        __builtin_amdgcn_s_setprio(1);
#pragma unroll
        for (int i = 0; i < 4; ++i)
#pragma unroll
            for (int j = 0; j < 4; ++j)
                acc[i][j] = __builtin_amdgcn_mfma_f32_16x16x32_bf16(af[i], bf[j], acc[i][j], 0, 0, 0);
        __builtin_amdgcn_s_setprio(0);
        asm volatile("s_waitcnt vmcnt(3)" ::: "memory");
        __builtin_amdgcn_s_barrier();
    }
    asm volatile("s_waitcnt vmcnt(0)" ::: "memory");

#pragma unroll
    for (int nt = 0; nt < 4; ++nt) {
        int n_g = n0 + wn * 64 + nt * 16 + l16;
        float bv = bias[n_g];
#pragma unroll
        for (int mt = 0; mt < 4; ++mt)
#pragma unroll
            for (int r = 0; r < 4; ++r) {
                int m_g = m0 + wm * 64 + mt * 16 + quad * 4 + r;
                out[(size_t)m_g * DMODEL + n_g] = acc[mt][nt][r] + bv;
            }
    }
}

extern "C" void kernel_launch(void* const* d_in, const int* in_sizes, int n_in,
                              void* d_out, int out_size, void* d_ws, size_t ws_size,
                              hipStream_t stream) {
    const float* query = (const float*)d_in[0];
    const float* Wq = (const float*)d_in[1];
    const float* bq = (const float*)d_in[2];
    const float* Wk = (const float*)d_in[3];
    const float* bk = (const float*)d_in[4];
    const float* Wv = (const float*)d_in[5];
    const float* bv = (const float*)d_in[6];
    const float* Wo = (const float*)d_in[7];
    const float* bo = (const float*)d_in[8];
    float* out = (float*)d_out;

    unsigned short* ws  = (unsigned short*)d_ws;
    unsigned short* xb  = ws;                       // 8192*1024
    unsigned short* wqb = xb  + (size_t)8388608;    // 1024*1024 each, CONTIGUOUS wq|wk|wv|wo
    unsigned short* wkb = wqb + 1048576;
    unsigned short* wvb = wkb + 1048576;
    unsigned short* wob = wvb + 1048576;
    unsigned short* Qb  = wob + 1048576;            // [bh][l][d]
    unsigned short* Kb  = Qb  + 8388608;
    unsigned short* Vr  = Kb  + 8388608;            // [bh][d][l] (written directly by proj)
    unsigned short* Ab  = Vr  + 8388608;            // [b][l][h*d]
    float* rope = (float*)(Ab + 8388608);           // 2048*32 float2 = 512 KB

    (void)wkb; (void)wvb;

    // fused prep: X cvt + weight cvt + rope table (one dispatch, 12545 blocks)
    prep<<<12545, 256, 0, stream>>>(query, Wq, Wk, Wv, Wo, xb, wqb, rope);

    // fused QKV GEMM: M=8192 x N=3072, 128x256 tiles -> grid (12, 64) = 768 blocks
    proj_qkv<<<dim3(12, 64), 512, 0, stream>>>(xb, wqb, bq, bk, bv, rope, Qb, Kb, Vr);
    // grid (bh, pair): 128 q-rows/block; s=pair & 15-pair -> 36 tile-units each
    attn_fwd<<<dim3(64, 8), 256, 0, stream>>>(Qb, Kb, Vr, Ab);
    // output GEMM: M=8192 x N=1024, 128x256 tiles -> grid (4, 64) = 256 blocks
    out_gemm<<<dim3(4, 64), 512, 0, stream>>>(Ab, wob, bo, out);
}